// Round 17
// baseline (431.405 us; speedup 1.0000x reference)
//
#include <hip/hip_runtime.h>
#include <hip/hip_bf16.h>

#define NN      50000
#define EE      800000
#define ETOT    (EE + NN)        // + self loops
#define GG      64
#define HEADS   4
#define HID     25
#define DENSE   100
#define IN_DIM  128
#define OUT_DIM 2
#define NPC     5
#define NUM_PROT (OUT_DIM * NPC)
#define NCHUNK  ((NN + 255) / 256)

#define NEG_INF (-3.402823466e38f)

// ---------------- CSR build ----------------
__global__ void k_count(const int* __restrict__ ei, int* __restrict__ cnt, int* __restrict__ pos) {
    int e = blockIdx.x * blockDim.x + threadIdx.x;
    if (e >= ETOT) return;
    int dst = (e < EE) ? ei[EE + e] : (e - EE);
    pos[e] = atomicAdd(&cnt[dst], 1);
}

__global__ void k_scan1(const int* __restrict__ cnt, int* __restrict__ csum) {
    __shared__ int sh[256];
    int i = blockIdx.x * 256 + threadIdx.x;
    int v = (i < NN) ? cnt[i] : 0;
    sh[threadIdx.x] = v;
    __syncthreads();
    for (int s = 128; s > 0; s >>= 1) {
        if (threadIdx.x < s) sh[threadIdx.x] += sh[threadIdx.x + s];
        __syncthreads();
    }
    if (threadIdx.x == 0) csum[blockIdx.x] = sh[0];
}

__global__ void k_scan2(int* __restrict__ csum) {
    __shared__ int sh[256];
    int tid = threadIdx.x;
    int v = (tid < NCHUNK) ? csum[tid] : 0;
    sh[tid] = v;
    __syncthreads();
    for (int s = 1; s < 256; s <<= 1) {
        int t = (tid >= s) ? sh[tid - s] : 0;
        __syncthreads();
        sh[tid] += t;
        __syncthreads();
    }
    if (tid < NCHUNK) csum[tid] = sh[tid] - v;     // exclusive
    if (tid == NCHUNK) csum[NCHUNK] = sh[255];     // total
}

__global__ void k_scan3(const int* __restrict__ cnt, const int* __restrict__ csum, int* __restrict__ offs) {
    __shared__ int sh[256];
    int i = blockIdx.x * 256 + threadIdx.x;
    int v = (i < NN) ? cnt[i] : 0;
    sh[threadIdx.x] = v;
    __syncthreads();
    for (int s = 1; s < 256; s <<= 1) {
        int t = (threadIdx.x >= s) ? sh[threadIdx.x - s] : 0;
        __syncthreads();
        sh[threadIdx.x] += t;
        __syncthreads();
    }
    int excl = sh[threadIdx.x] - v + csum[blockIdx.x];
    if (i <= NN) offs[i] = excl;
}

__global__ void k_scatter(const int* __restrict__ ei, const int* __restrict__ offs,
                          const int* __restrict__ pos, int* __restrict__ csr) {
    int e = blockIdx.x * blockDim.x + threadIdx.x;
    if (e >= ETOT) return;
    int src, dst;
    if (e < EE) { src = ei[e]; dst = ei[EE + e]; }
    else        { src = dst = e - EE; }
    csr[offs[dst] + pos[e]] = src;
}

// ---------------- graph boundaries (batch is sorted) ----------------
__global__ void k_bounds(const int* __restrict__ batch, int* __restrict__ gstart) {
    int n = blockIdx.x * blockDim.x + threadIdx.x;
    if (n >= NN) return;
    int b = batch[n];
    if (n == 0) {
        for (int g = 0; g <= b; g++) gstart[g] = 0;
    } else {
        int pb = batch[n - 1];
        for (int g = pb + 1; g <= b; g++) gstart[g] = n;
    }
    if (n == NN - 1) {
        for (int g = b + 1; g <= GG; g++) gstart[g] = NN;
    }
}

// ---------------- GEMM: H = X @ W  ([N,DIN] x [DIN,100]) ----------------
// Champion structure + COLUMN-SPLIT grid: (391, 2) blocks, each 128 rows x
// 64-col slice. Identical Xs layout (pad 132, conflict-free); Ws halves to
// 12.3 KB -> 29 KB total, 5 blocks/CU by LDS, 3.05 blocks/CU by grid
// (vs 1.53 before: makespan 2T -> ~1.5T, 3 waves/SIMD latency hiding).
// T14 pipeline: chunk c+1's X loads into registers during chunk c compute.
template <int DIN, int KC>
__device__ __forceinline__ void gemm_body(const float* __restrict__ X,
                                          const float* __restrict__ W,
                                          float* __restrict__ H) {
    constexpr int NCH = DIN / KC;     // 128/32 = 4, 100/20 = 5
    constexpr int KQ  = KC / 4;       // 8, 5
    constexpr int XN  = 128 * KQ;     // float4 stage slots
    constexpr int XIT = (XN + 255) / 256;
    constexpr int WIT = KC * 64 / 256;   // 64-col slice: 8, 5
    constexpr int XP  = 132;          // Xs k-row stride (16B-aligned)
    constexpr int WP  = 96;           // Ws k-row stride: 8 groups * 12
    __shared__ float Xs[KC * XP];
    __shared__ float Ws[KC * WP];
    const int tid = threadIdx.x;
    const int tr = tid >> 3;          // 0..31 -> rows tr*4..+3
    const int tc = tid & 7;           // 0..7  -> cols cbase + tc*8..+7
    const int node0 = blockIdx.x * 128;
    const int cbase = blockIdx.y * 64;

    float4 xreg[XIT];
    float  wreg[WIT];

    auto load_chunk = [&](int ch) {
        const int k0 = ch * KC;
        #pragma unroll
        for (int i = 0; i < XIT; ++i) {
            int idx = tid + 256 * i;
            if ((XN % 256 == 0) || idx < XN) {
                int row = idx / KQ, kq = idx - row * KQ;
                int gr = node0 + row;
                float4 v = {0.f, 0.f, 0.f, 0.f};
                if (gr < NN) v = *reinterpret_cast<const float4*>(&X[(size_t)gr * DIN + k0 + kq * 4]);
                xreg[i] = v;
            }
        }
        #pragma unroll
        for (int i = 0; i < WIT; ++i) {
            int idx = tid + 256 * i;
            int k = idx >> 6, c = idx & 63;
            int col = cbase + c;
            wreg[i] = (col < 100) ? W[(size_t)(k0 + k) * 100 + col] : 0.f;
        }
    };
    auto store_chunk = [&]() {
        #pragma unroll
        for (int i = 0; i < XIT; ++i) {
            int idx = tid + 256 * i;
            if ((XN % 256 == 0) || idx < XN) {
                int row = idx / KQ, kq = idx - row * KQ;
                Xs[(kq * 4 + 0) * XP + row] = xreg[i].x;
                Xs[(kq * 4 + 1) * XP + row] = xreg[i].y;
                Xs[(kq * 4 + 2) * XP + row] = xreg[i].z;
                Xs[(kq * 4 + 3) * XP + row] = xreg[i].w;
            }
        }
        #pragma unroll
        for (int i = 0; i < WIT; ++i) {
            int idx = tid + 256 * i;
            int k = idx >> 6, c = idx & 63;
            Ws[k * WP + (c >> 3) * 12 + (c & 7)] = wreg[i];
        }
    };

    float acc[4][8] = {};
    load_chunk(0);
    for (int ch = 0; ch < NCH; ++ch) {
        __syncthreads();               // previous compute done; LDS reusable
        store_chunk();
        __syncthreads();
        if (ch + 1 < NCH) load_chunk(ch + 1);   // in flight during compute
        #pragma unroll 4
        for (int k = 0; k < KC; ++k) {
            float4 xa = *reinterpret_cast<const float4*>(&Xs[k * XP + tr * 4]);
            float4 wa = *reinterpret_cast<const float4*>(&Ws[k * WP + tc * 12]);
            float4 wb = *reinterpret_cast<const float4*>(&Ws[k * WP + tc * 12 + 4]);
            float xs[4] = {xa.x, xa.y, xa.z, xa.w};
            float ws[8] = {wa.x, wa.y, wa.z, wa.w, wb.x, wb.y, wb.z, wb.w};
            #pragma unroll
            for (int r = 0; r < 4; ++r) {
                #pragma unroll
                for (int c = 0; c < 8; ++c) {
                    acc[r][c] += xs[r] * ws[c];
                }
            }
        }
    }
    const int c0 = cbase + tc * 8;
    if (c0 < 100) {
        #pragma unroll
        for (int r = 0; r < 4; ++r) {
            int row = node0 + tr * 4 + r;
            if (row < NN) {
                float* hp = &H[(size_t)row * 100 + c0];
                float4 v0 = {acc[r][0], acc[r][1], acc[r][2], acc[r][3]};
                *reinterpret_cast<float4*>(hp) = v0;
                if (c0 + 4 < 100) {
                    float4 v1 = {acc[r][4], acc[r][5], acc[r][6], acc[r][7]};
                    *reinterpret_cast<float4*>(hp + 4) = v1;
                }
            }
        }
    }
}

// distinct names per layer so rocprof separates them
__global__ __launch_bounds__(256) void k_gemm0(const float* __restrict__ X, const float* __restrict__ W, float* __restrict__ H) {
    gemm_body<IN_DIM, 32>(X, W, H);
}
__global__ __launch_bounds__(256) void k_gemm1(const float* __restrict__ X, const float* __restrict__ W, float* __restrict__ H) {
    gemm_body<DENSE, 20>(X, W, H);
}
__global__ __launch_bounds__(256) void k_gemm2(const float* __restrict__ X, const float* __restrict__ W, float* __restrict__ H) {
    gemm_body<DENSE, 20>(X, W, H);
}

// ---------------- per-node attention logits: es/ed ----------------
__global__ void k_esed(const float* __restrict__ H, const float* __restrict__ AS,
                       const float* __restrict__ AD, float* __restrict__ es, float* __restrict__ ed) {
    int t = blockIdx.x * blockDim.x + threadIdx.x;
    if (t >= NN * HEADS) return;
    int n = t >> 2, hd = t & 3;
    const float* hr = H + (size_t)n * 100 + hd * 25;
    const float* as = AS + hd * 25;
    const float* ad = AD + hd * 25;
    float s1 = 0.f, s2 = 0.f;
    #pragma unroll
    for (int d = 0; d < 25; d++) {
        float v = hr[d];
        s1 += v * as[d];
        s2 += v * ad[d];
    }
    es[t] = s1;
    ed[t] = s2;
}

// ---------------- phase A: per-node softmax stats + per-edge weights ----------------
// one wave per node; lane = edge_slot(16) * 4 + head(4).
// First 3 per-lane 'a' values cached in named scalars (rule-#20 safe): weight
// pass skips the second csr+es gather for deg <= 48; recompute fallback beyond.
__global__ __launch_bounds__(256) void k_msum(const float* __restrict__ es,
                                              const float* __restrict__ ed,
                                              const int* __restrict__ offs,
                                              const int* __restrict__ csr,
                                              float* __restrict__ wv) {
    int wid = threadIdx.x >> 6;
    int lane = threadIdx.x & 63;
    int n = blockIdx.x * 4 + wid;
    if (n >= NN) return;
    int el = lane >> 2, hd = lane & 3;
    int beg = offs[n], end = offs[n + 1];
    float edh = ed[n * 4 + hd];
    float m = NEG_INF, s = 0.f;
    float a0 = 0.f, a1 = 0.f, a2 = 0.f;
    int i = 0;
    for (int e = beg + el; e < end; e += 16) {
        int si = csr[e];
        float a = es[si * 4 + hd] + edh;
        a = fmaxf(a, 0.2f * a);          // leaky relu
        if (i == 0) a0 = a; else if (i == 1) a1 = a; else if (i == 2) a2 = a;
        ++i;
        float nm = fmaxf(m, a);
        float sc = __expf(m - nm);       // m=-inf, nm finite -> 0, no NaN
        s = s * sc + __expf(a - nm);
        m = nm;
    }
    // butterfly merge over edge-slot bits (lane bits 2..5)
    #pragma unroll
    for (int mask = 4; mask <= 32; mask <<= 1) {
        float mo = __shfl_xor(m, mask, 64);
        float so = __shfl_xor(s, mask, 64);
        float nm = fmaxf(m, mo);
        float f1 = (m  > NEG_INF) ? __expf(m  - nm) : 0.f;
        float f2 = (mo > NEG_INF) ? __expf(mo - nm) : 0.f;
        s = s * f1 + so * f2;
        m = nm;
    }
    float invs = 1.f / (s + 1e-16f);
    // weight pass: cached 'a' for first 3 iterations, recompute beyond
    i = 0;
    for (int e = beg + el; e < end; e += 16) {
        float a;
        if (i == 0)      a = a0;
        else if (i == 1) a = a1;
        else if (i == 2) a = a2;
        else {
            int si = csr[e];
            a = es[si * 4 + hd] + edh;
            a = fmaxf(a, 0.2f * a);
        }
        ++i;
        wv[(size_t)e * 4 + hd] = __expf(a - m) * invs;
    }
}

// ---------------- phase B: weighted gather-accumulate (round-4 proven shape) ----------------
// 2 nodes per block (1 wave each); 50 lanes x float2 = one 400B row per request.
// Predicated unroll-8: 8 independent gathers always in flight, no serial tail.
// Measured: 64 us, 183 MB FETCH ~ 8-XCD scatter floor, 5.9 TB/s delivered.
__global__ __launch_bounds__(128) void k_acc(const float* __restrict__ H,
                                             const float* __restrict__ wv,
                                             const int* __restrict__ offs,
                                             const int* __restrict__ csr,
                                             const float* __restrict__ bias,
                                             float* __restrict__ out) {
    int wid = threadIdx.x >> 6;
    int lane = threadIdx.x & 63;
    int n = blockIdx.x * 2 + wid;
    if (n >= NN || lane >= 50) return;
    int d0 = lane * 2;
    int h0 = d0 / 25, h1 = (d0 + 1) / 25;
    int beg = offs[n], end = offs[n + 1];
    float ax = 0.f, ay = 0.f;
    for (int e = beg; e < end; e += 8) {
        #pragma unroll
        for (int u = 0; u < 8; ++u) {
            int ee = e + u;
            int ec = (ee < end) ? ee : beg;          // clamp to a valid slot
            int idx = csr[ec];
            float wx = wv[ec * 4 + h0];
            float wy = wv[ec * 4 + h1];
            if (ee >= end) { wx = 0.f; wy = 0.f; }   // zero weight for phantom lanes
            float2 xv = *reinterpret_cast<const float2*>(&H[idx * 100 + d0]);
            ax += wx * xv.x;
            ay += wy * xv.y;
        }
    }
    float2 b = *reinterpret_cast<const float2*>(&bias[d0]);
    float2 o = {fmaxf(ax + b.x, 0.f), fmaxf(ay + b.y, 0.f)};
    *reinterpret_cast<float2*>(&out[n * 100 + d0]) = o;
}

// ---------------- global max pool (2-level) ----------------
__global__ void k_pool1(const float* __restrict__ NE, const int* __restrict__ gstart,
                        float* __restrict__ part) {
    int g = blockIdx.x >> 3, c = blockIdx.x & 7;
    int d = threadIdx.x;
    if (d >= 100) return;
    int s0 = gstart[g], s1 = gstart[g + 1];
    int len = s1 - s0;
    int n0 = s0 + (int)((long long)len * c / 8);
    int n1 = s0 + (int)((long long)len * (c + 1) / 8);
    float vm = NEG_INF;
    for (int n = n0; n < n1; n++) vm = fmaxf(vm, NE[(size_t)n * 100 + d]);
    part[(size_t)(g * 8 + c) * 100 + d] = vm;
}

__global__ void k_pool2(const float* __restrict__ part, float* __restrict__ GE) {
    int g = blockIdx.x;
    int d = threadIdx.x;
    if (d >= 100) return;
    float vm = NEG_INF;
    for (int c = 0; c < 8; c++) vm = fmaxf(vm, part[(size_t)(g * 8 + c) * 100 + d]);
    GE[(size_t)g * 100 + d] = vm;
}

// ---------------- prototype head ----------------
__global__ void k_head(const float* __restrict__ GE, const float* __restrict__ P,
                       const float* __restrict__ LW, float* __restrict__ logits,
                       float* __restrict__ probs, float* __restrict__ dist) {
    int g = blockIdx.x;
    __shared__ float ge[100];
    __shared__ float sims[NUM_PROT];
    __shared__ float lg[OUT_DIM];
    int t = threadIdx.x;
    if (t < 100) ge[t] = GE[(size_t)g * 100 + t];
    __syncthreads();
    if (t < NUM_PROT) {
        float dot = 0.f, pn = 0.f, gn = 0.f;
        for (int d = 0; d < 100; d++) {
            float pv = P[t * 100 + d];
            float gv = ge[d];
            dot += gv * pv;
            pn += pv * pv;
            gn += gv * gv;
        }
        float ds = gn - 2.f * dot + pn;
        dist[g * NUM_PROT + t] = ds;
        sims[t] = logf((ds + 1.f) / (ds + 1e-4f));
    }
    __syncthreads();
    if (t < OUT_DIM) {
        float l = 0.f;
        for (int p = 0; p < NUM_PROT; p++) l += sims[p] * LW[t * NUM_PROT + p];
        lg[t] = l;
        logits[g * OUT_DIM + t] = l;
    }
    __syncthreads();
    if (t == 0) {
        float mm = fmaxf(lg[0], lg[1]);
        float e0 = __expf(lg[0] - mm), e1 = __expf(lg[1] - mm);
        float inv = 1.f / (e0 + e1);
        probs[g * OUT_DIM + 0] = e0 * inv;
        probs[g * OUT_DIM + 1] = e1 * inv;
    }
}

extern "C" void kernel_launch(void* const* d_in, const int* in_sizes, int n_in,
                              void* d_out, int out_size, void* d_ws, size_t ws_size,
                              hipStream_t stream) {
    const float* x     = (const float*)d_in[0];
    const int*   ei    = (const int*)d_in[1];
    const int*   batch = (const int*)d_in[2];
    const float* Wm[3]  = {(const float*)d_in[3],  (const float*)d_in[7],  (const float*)d_in[11]};
    const float* ASm[3] = {(const float*)d_in[4],  (const float*)d_in[8],  (const float*)d_in[12]};
    const float* ADm[3] = {(const float*)d_in[5],  (const float*)d_in[9],  (const float*)d_in[13]};
    const float* Bm[3]  = {(const float*)d_in[6],  (const float*)d_in[10], (const float*)d_in[14]};
    const float* P  = (const float*)d_in[15];
    const float* LW = (const float*)d_in[16];

    float* out = (float*)d_out;
    float* logits  = out;                                   // [64,2]
    float* probs   = out + GG * OUT_DIM;                    // [64,2]
    float* nodeEmb = out + 2 * GG * OUT_DIM;                // [N,100]
    float* GE      = nodeEmb + (size_t)NN * DENSE;          // [64,100]
    float* disto   = GE + GG * DENSE;                       // [64,10]

    // workspace carve-up
    char* w = (char*)d_ws;
    size_t off = 0;
    auto carve = [&](size_t bytes) -> void* {
        void* p = w + off;
        off += (bytes + 15) & ~(size_t)15;
        return p;
    };
    float* hA   = (float*)carve((size_t)NN * DENSE * 4);
    float* es   = (float*)carve((size_t)NN * HEADS * 4);
    float* ed   = (float*)carve((size_t)NN * HEADS * 4);
    int* cnt    = (int*)carve((size_t)NN * 4);
    int* offs   = (int*)carve((size_t)(NN + 1) * 4);
    int* pos    = (int*)carve((size_t)ETOT * 4);
    int* csr    = (int*)carve((size_t)ETOT * 4);
    int* csum   = (int*)carve((size_t)(NCHUNK + 1) * 4);
    int* gstart = (int*)carve((size_t)(GG + 1) * 4);
    float* part = (float*)carve((size_t)GG * 8 * DENSE * 4);
    float* wv   = (float*)carve((size_t)ETOT * HEADS * 4);   // per-edge weights
    (void)in_sizes; (void)n_in; (void)out_size; (void)ws_size;

    // ---- CSR build (once, reused for all 3 layers) ----
    hipMemsetAsync(cnt, 0, (size_t)NN * 4, stream);
    k_count<<<(ETOT + 255) / 256, 256, 0, stream>>>(ei, cnt, pos);
    k_scan1<<<NCHUNK, 256, 0, stream>>>(cnt, csum);
    k_scan2<<<1, 256, 0, stream>>>(csum);
    k_scan3<<<NCHUNK, 256, 0, stream>>>(cnt, csum, offs);
    k_scatter<<<(ETOT + 255) / 256, 256, 0, stream>>>(ei, offs, pos, csr);
    k_bounds<<<(NN + 255) / 256, 256, 0, stream>>>(batch, gstart);

    const dim3 gemmGrid((NN + 127) / 128, 2);   // column-split: 391 x 2
    const int esedGrid = (NN * HEADS + 255) / 256;
    const int msumGrid = (NN + 3) / 4;
    const int accGrid  = (NN + 1) / 2;

    const float* layerIn = x;
    for (int l = 0; l < 3; ++l) {
        if (l == 0)      k_gemm0<<<gemmGrid, 256, 0, stream>>>(layerIn, Wm[l], hA);
        else if (l == 1) k_gemm1<<<gemmGrid, 256, 0, stream>>>(layerIn, Wm[l], hA);
        else             k_gemm2<<<gemmGrid, 256, 0, stream>>>(layerIn, Wm[l], hA);
        k_esed<<<esedGrid, 256, 0, stream>>>(hA, ASm[l], ADm[l], es, ed);
        k_msum<<<msumGrid, 256, 0, stream>>>(es, ed, offs, csr, wv);
        k_acc<<<accGrid, 128, 0, stream>>>(hA, wv, offs, csr, Bm[l], nodeEmb);
        layerIn = nodeEmb;
    }

    // ---- pooling ----
    k_pool1<<<GG * 8, 128, 0, stream>>>(nodeEmb, gstart, part);
    k_pool2<<<GG, 128, 0, stream>>>(part, GE);

    // ---- prototype head ----
    k_head<<<GG, 128, 0, stream>>>(GE, P, LW, logits, probs, disto);
}